// Round 10
// baseline (322.419 us; speedup 1.0000x reference)
//
#include <hip/hip_runtime.h>
#include <hip/hip_bf16.h>

#define BB 512
#define TT 300
#define IN_S 128
#define IN_D 64
#define HS 256
#define HD 128
#define CD 512  // 2*HD + HS

typedef __attribute__((ext_vector_type(8))) short bf16x8;
typedef __attribute__((ext_vector_type(4))) float f32x4;
typedef __attribute__((ext_vector_type(4))) unsigned uint4_t;
typedef unsigned short ushort_t;

static __device__ __forceinline__ ushort_t f2bf(float x) {
    unsigned u = __builtin_bit_cast(unsigned, x);
    unsigned r = (u + 0x7FFFu + ((u >> 16) & 1u)) >> 16;  // RNE
    return (ushort_t)r;
}
static __device__ __forceinline__ float bflo(unsigned u) {
    return __builtin_bit_cast(float, u << 16);
}
static __device__ __forceinline__ float bfhi(unsigned u) {
    return __builtin_bit_cast(float, u & 0xffff0000u);
}
static __device__ __forceinline__ unsigned cvt_pk(float lo, float hi) {
    unsigned r;
    asm("v_cvt_pk_bf16_f32 %0, %1, %2" : "=v"(r) : "v"(lo), "v"(hi));
    return r;
}

// ---------------------------------------------------------------------------
// prep: f32 weights -> bf16 workspace copies; fused RNN bias sums.
// ---------------------------------------------------------------------------
__global__ __launch_bounds__(256) void prep_kernel(
    const float* __restrict__ wd, const float* __restrict__ wihf, const float* __restrict__ wihb,
    const float* __restrict__ whhf, const float* __restrict__ whhb,
    const float* __restrict__ bif, const float* __restrict__ bhf,
    const float* __restrict__ bib, const float* __restrict__ bhb,
    ushort_t* __restrict__ wd_bf, ushort_t* __restrict__ wihf_bf, ushort_t* __restrict__ wihb_bf,
    ushort_t* __restrict__ whhf_bf, ushort_t* __restrict__ whhb_bf,
    float* __restrict__ bsf, float* __restrict__ bsb)
{
    const int i = blockIdx.x * 256 + threadIdx.x;  // < 16384
    if (i < HD * IN_D) wd_bf[i] = f2bf(wd[i]);
    wihf_bf[i] = f2bf(wihf[i]);
    wihb_bf[i] = f2bf(wihb[i]);
    whhf_bf[i] = f2bf(whhf[i]);
    whhb_bf[i] = f2bf(whhb[i]);
    if (i < HD) { bsf[i] = bif[i] + bhf[i]; bsb[i] = bib[i] + bhb[i]; }
}

// ---------------------------------------------------------------------------
// Kernel A (validated r0): static MLP + static head dot.
// ---------------------------------------------------------------------------
__global__ __launch_bounds__(256) void static_head_kernel(
    const float* __restrict__ xs, const int* __restrict__ norder,
    const float* __restrict__ w1, const float* __restrict__ b1,
    const float* __restrict__ w2, const float* __restrict__ b2,
    const float* __restrict__ fcw, const float* __restrict__ fcb,
    float* __restrict__ ds)
{
    __shared__ float xb[IN_S];
    __shared__ float s1[HS];
    __shared__ float red[4];
    const int b = blockIdx.x, tid = threadIdx.x;
    if (tid < IN_S) xb[tid] = xs[(size_t)b * IN_S + tid];
    __syncthreads();

    float a0 = 0.f, a1 = 0.f, a2 = 0.f, a3 = 0.f;
    {
        const float4* wsrc = (const float4*)(w1 + (size_t)tid * IN_S);
        const float4* x4 = (const float4*)xb;
#pragma unroll
        for (int i = 0; i < IN_S / 4; ++i) {
            float4 w = wsrc[i], x = x4[i];
            a0 = fmaf(w.x, x.x, a0); a1 = fmaf(w.y, x.y, a1);
            a2 = fmaf(w.z, x.z, a2); a3 = fmaf(w.w, x.w, a3);
        }
    }
    s1[tid] = fmaxf(b1[tid] + ((a0 + a1) + (a2 + a3)), 0.f);
    __syncthreads();

    a0 = a1 = a2 = a3 = 0.f;
    {
        const float4* wsrc = (const float4*)(w2 + (size_t)tid * HS);
        const float4* x4 = (const float4*)s1;
#pragma unroll
        for (int i = 0; i < HS / 4; ++i) {
            float4 w = wsrc[i], x = x4[i];
            a0 = fmaf(w.x, x.x, a0); a1 = fmaf(w.y, x.y, a1);
            a2 = fmaf(w.z, x.z, a2); a3 = fmaf(w.w, x.w, a3);
        }
    }
    float s2 = fmaxf(b2[tid] + ((a0 + a1) + (a2 + a3)), 0.f);

    const int n = norder[b];
    float p = s2 * fcw[(size_t)n * CD + tid];
#pragma unroll
    for (int o = 32; o >= 1; o >>= 1) p += __shfl_down(p, o);
    if ((tid & 63) == 0) red[tid >> 6] = p;
    __syncthreads();
    if (tid == 0) ds[b] = red[0] + red[1] + red[2] + red[3] + fcb[n];
}

// ---------------------------------------------------------------------------
// proj (validated r2, unchanged): MFMA bf16 projection + RNN input precompute.
// ---------------------------------------------------------------------------
__global__ __launch_bounds__(256) void proj_kernel(
    const float* __restrict__ xd, const ushort_t* __restrict__ wd_bf,
    const float* __restrict__ bd,
    const ushort_t* __restrict__ wihf_bf, const ushort_t* __restrict__ wihb_bf,
    const float* __restrict__ bsf, const float* __restrict__ bsb,
    ushort_t* __restrict__ preF, ushort_t* __restrict__ preB)
{
    __shared__ char lds[49152];
    char* dbase = lds;
    char* xbase = lds + 32768;
    const int tid = threadIdx.x;
    const int m0 = blockIdx.x * 128;

    {
        const int row = tid >> 1, half = tid & 1;
        const int swz = (row & 7) << 4;
        const float4* src = (const float4*)(xd + (size_t)(m0 + row) * IN_D + half * 32);
#pragma unroll
        for (int i = 0; i < 4; ++i) {
            float4 a = src[2 * i], b = src[2 * i + 1];
            bf16x8 v;
            v[0] = (short)f2bf(a.x); v[1] = (short)f2bf(a.y);
            v[2] = (short)f2bf(a.z); v[3] = (short)f2bf(a.w);
            v[4] = (short)f2bf(b.x); v[5] = (short)f2bf(b.y);
            v[6] = (short)f2bf(b.z); v[7] = (short)f2bf(b.w);
            *(bf16x8*)(xbase + ((row * 128 + half * 64 + i * 16) ^ swz)) = v;
        }
    }
    __syncthreads();

    const int w = tid >> 6, l = tid & 63;
    const int lr = l & 15, lg = l >> 4;

    f32x4 acc[2][8];
#pragma unroll
    for (int mt = 0; mt < 2; ++mt)
#pragma unroll
        for (int nt = 0; nt < 8; ++nt) acc[mt][nt] = (f32x4){0.f, 0.f, 0.f, 0.f};

    for (int kk = 0; kk < 2; ++kk) {
        bf16x8 a[2], b[8];
#pragma unroll
        for (int mt = 0; mt < 2; ++mt) {
            const int row = (w * 2 + mt) * 16 + lr;
            a[mt] = *(const bf16x8*)(xbase + ((row * 128 + kk * 64 + lg * 16) ^ ((row & 7) << 4)));
        }
#pragma unroll
        for (int nt = 0; nt < 8; ++nt)
            b[nt] = *(const bf16x8*)(wd_bf + (nt * 16 + lr) * IN_D + kk * 32 + lg * 8);
#pragma unroll
        for (int mt = 0; mt < 2; ++mt)
#pragma unroll
            for (int nt = 0; nt < 8; ++nt)
                acc[mt][nt] = __builtin_amdgcn_mfma_f32_16x16x32_bf16(a[mt], b[nt], acc[mt][nt], 0, 0, 0);
    }
#pragma unroll
    for (int nt = 0; nt < 8; ++nt) {
        const float bj = bd[nt * 16 + lr];
        const int col2 = (nt * 16 + lr) * 2;
#pragma unroll
        for (int mt = 0; mt < 2; ++mt)
#pragma unroll
            for (int r = 0; r < 4; ++r) {
                const int row = (w * 2 + mt) * 16 + lg * 4 + r;
                const float v = fmaxf(acc[mt][nt][r] + bj, 0.f);
                *(ushort_t*)(dbase + ((row * 256 + col2) ^ ((row & 7) << 4))) = f2bf(v);
            }
    }
    __syncthreads();

#pragma unroll
    for (int mat = 0; mat < 2; ++mat) {
        const ushort_t* wm = mat ? wihb_bf : wihf_bf;
        const float* bs = mat ? bsb : bsf;
        ushort_t* outp = mat ? preB : preF;

        f32x4 acc2[2][8];
#pragma unroll
        for (int mt = 0; mt < 2; ++mt)
#pragma unroll
            for (int nt = 0; nt < 8; ++nt) acc2[mt][nt] = (f32x4){0.f, 0.f, 0.f, 0.f};

        for (int kk = 0; kk < 4; ++kk) {
            bf16x8 a[2], b[8];
#pragma unroll
            for (int mt = 0; mt < 2; ++mt) {
                const int row = (w * 2 + mt) * 16 + lr;
                a[mt] = *(const bf16x8*)(dbase + ((row * 256 + kk * 64 + lg * 16) ^ ((row & 7) << 4)));
            }
#pragma unroll
            for (int nt = 0; nt < 8; ++nt)
                b[nt] = *(const bf16x8*)(wm + (nt * 16 + lr) * HD + kk * 32 + lg * 8);
#pragma unroll
            for (int mt = 0; mt < 2; ++mt)
#pragma unroll
                for (int nt = 0; nt < 8; ++nt)
                    acc2[mt][nt] = __builtin_amdgcn_mfma_f32_16x16x32_bf16(a[mt], b[nt], acc2[mt][nt], 0, 0, 0);
        }
        float bsv[8];
#pragma unroll
        for (int nt = 0; nt < 8; ++nt) bsv[nt] = bs[nt * 16 + lr];
#pragma unroll
        for (int mt = 0; mt < 2; ++mt)
#pragma unroll
            for (int r = 0; r < 4; ++r) {
                const unsigned m = (unsigned)(m0 + (w * 2 + mt) * 16 + lg * 4 + r);
                const unsigned s = m / TT, t = m % TT;
                ushort_t* rowp = outp + ((size_t)t * BB + s) * HD;
#pragma unroll
                for (int nt = 0; nt < 8; ++nt)
                    rowp[nt * 16 + lr] = f2bf(acc2[mt][nt][r] + bsv[nt]);
            }
    }
}

// ---------------------------------------------------------------------------
// rnn v10: v9's 4-wave cooperative step, but BOTH directions of a sample
// group share one 512-thread block (8 waves, 32 blocks): waves 0-3 = fwd,
// waves 4-7 = bwd, each chain with its own 2x4KB LDS double-buffer.
// 2 waves/SIMD from INDEPENDENT chains hide each other's ds_read/MFMA/
// barrier latency. Per-wave code identical to validated v9.
// ---------------------------------------------------------------------------
__global__ __launch_bounds__(512, 1) void rnn_kernel(
    const ushort_t* __restrict__ preF, const ushort_t* __restrict__ preB,
    ushort_t* __restrict__ hF, ushort_t* __restrict__ hB,
    const ushort_t* __restrict__ whhF, const ushort_t* __restrict__ whhB)
{
    __shared__ char hlds[16384];  // [2 chains][2 bufs][16 samples][128 j] bf16
    const int bid = blockIdx.x;       // 32 blocks = 32 sample groups
    const int s0 = bid * 16;

    const int tid = threadIdx.x;
    const int w = tid >> 6;           // 0..7
    const int dir = w >> 2;           // 0 = fwd, 1 = bwd
    const int wl = w & 3;             // wave within chain
    const int l = tid & 63;
    const int lr = l & 15, lg = l >> 4;

    const ushort_t* __restrict__ pre = dir ? preB : preF;
    ushort_t* __restrict__ hout = dir ? hB : hF;
    const ushort_t* __restrict__ whh = dir ? whhB : whhF;
    char* hbase = hlds + dir * 8192;

    // this wave's two j-tiles
    const int jt0 = 2 * wl, jt1 = 2 * wl + 1;
    const int jb0 = (jt0 & 3) * 32 + lg * 8 + (jt0 >> 2) * 4;
    const int jb1 = (jt1 & 3) * 32 + lg * 8 + (jt1 >> 2) * 4;

    // A fragments (permuted rows): row = pi(jt, lr)
    bf16x8 A0[4], A1[4];
#pragma unroll
    for (int kk = 0; kk < 4; ++kk) {
        const int r0 = (jt0 & 3) * 32 + (lr >> 2) * 8 + (jt0 >> 2) * 4 + (lr & 3);
        const int r1 = (jt1 & 3) * 32 + (lr >> 2) * 8 + (jt1 >> 2) * 4 + (lr & 3);
        A0[kk] = *(const bf16x8*)(whh + (size_t)r0 * HD + kk * 32 + lg * 8);
        A1[kk] = *(const bf16x8*)(whh + (size_t)r1 * HD + kk * 32 + lg * 8);
    }

    const int dt = dir ? -1 : 1;
    const int t0 = dir ? (TT - 1) : 0;
    const int row_off = (s0 + lr) * HD;
    const int swz = (lr & 7) << 4;

    // zero this chain's h buffer 0 (h_{-1} = 0): 256 threads x 16B = 4096B
    *(float4*)(hbase + (tid & 255) * 16) = (float4){0.f, 0.f, 0.f, 0.f};

    // depth-3 register prefetch of pre quads (2 x uint2 per step)
    uint2 pA0, pA1, pB0, pB1, pC0, pC1;
    {
        const ushort_t* p0 = pre + (size_t)t0 * (BB * HD) + row_off;
        const ushort_t* p1 = pre + (size_t)(t0 + dt) * (BB * HD) + row_off;
        const ushort_t* p2 = pre + (size_t)(t0 + 2 * dt) * (BB * HD) + row_off;
        pA0 = *(const uint2*)(p0 + jb0); pA1 = *(const uint2*)(p0 + jb1);
        pB0 = *(const uint2*)(p1 + jb0); pB1 = *(const uint2*)(p1 + jb1);
        pC0 = *(const uint2*)(p2 + jb0); pC1 = *(const uint2*)(p2 + jb1);
    }
    __syncthreads();  // once before the loop: h buffers visible to all waves

    int t = t0;
    int cur = 0;

#define RNN_STEP(P0, P1)                                                       \
    {                                                                          \
        bf16x8 Bq[4];                                                          \
        _Pragma("unroll")                                                      \
        for (int kk = 0; kk < 4; ++kk)                                         \
            Bq[kk] = *(const bf16x8*)(hbase + cur * 4096 +                     \
                                      ((lr * 256 + kk * 64 + lg * 16) ^ swz)); \
        f32x4 acc0, acc1;                                                      \
        acc0[0] = bflo(P0.x); acc0[1] = bfhi(P0.x);                            \
        acc0[2] = bflo(P0.y); acc0[3] = bfhi(P0.y);                            \
        acc1[0] = bflo(P1.x); acc1[1] = bfhi(P1.x);                            \
        acc1[2] = bflo(P1.y); acc1[3] = bfhi(P1.y);                            \
        {                                                                      \
            const int tp = t + 3 * dt;                                         \
            const int tc = tp < 0 ? 0 : (tp >= TT ? TT - 1 : tp);              \
            const ushort_t* pb = pre + (size_t)tc * (BB * HD) + row_off;       \
            P0 = *(const uint2*)(pb + jb0);                                    \
            P1 = *(const uint2*)(pb + jb1);                                    \
        }                                                                      \
        _Pragma("unroll")                                                      \
        for (int kk = 0; kk < 4; ++kk) {                                       \
            acc0 = __builtin_amdgcn_mfma_f32_16x16x32_bf16(A0[kk], Bq[kk], acc0, 0, 0, 0); \
            acc1 = __builtin_amdgcn_mfma_f32_16x16x32_bf16(A1[kk], Bq[kk], acc1, 0, 0, 0); \
        }                                                                      \
        const float v00 = fmaxf(acc0[0], 0.f), v01 = fmaxf(acc0[1], 0.f);      \
        const float v02 = fmaxf(acc0[2], 0.f), v03 = fmaxf(acc0[3], 0.f);      \
        const float v10 = fmaxf(acc1[0], 0.f), v11 = fmaxf(acc1[1], 0.f);      \
        const float v12 = fmaxf(acc1[2], 0.f), v13 = fmaxf(acc1[3], 0.f);      \
        const uint2 q0 = {cvt_pk(v00, v01), cvt_pk(v02, v03)};                 \
        const uint2 q1 = {cvt_pk(v10, v11), cvt_pk(v12, v13)};                 \
        *(uint2*)(hbase + (cur ^ 1) * 4096 + ((lr * 256 + jb0 * 2) ^ swz)) = q0;\
        *(uint2*)(hbase + (cur ^ 1) * 4096 + ((lr * 256 + jb1 * 2) ^ swz)) = q1;\
        {                                                                      \
            ushort_t* hb = hout + (size_t)t * (BB * HD) + row_off;             \
            *(uint2*)(hb + jb0) = q0;                                          \
            *(uint2*)(hb + jb1) = q1;                                          \
        }                                                                      \
        asm volatile("s_waitcnt lgkmcnt(0)" ::: "memory");                     \
        __builtin_amdgcn_s_barrier();                                          \
        t += dt;                                                               \
        cur ^= 1;                                                              \
    }

    for (int it = 0; it < TT / 3; ++it) {
        RNN_STEP(pA0, pA1);
        RNN_STEP(pB0, pB1);
        RNN_STEP(pC0, pC1);
    }
#undef RNN_STEP
}

// ---------------------------------------------------------------------------
// dot (validated r2): out[s*T+t] = relu(ds[s] + hf[t,s,:].wgf + hb[t,s,:].wgb)
// ---------------------------------------------------------------------------
__global__ __launch_bounds__(256) void dot_kernel(
    const ushort_t* __restrict__ hF, const ushort_t* __restrict__ hB,
    const float* __restrict__ fcw, const int* __restrict__ norder,
    const float* __restrict__ ds, float* __restrict__ out)
{
    const int gw = blockIdx.x * 4 + (threadIdx.x >> 6);  // < 2560
    const int s = gw / 5, chunk = gw % 5;
    const int l = threadIdx.x & 63, lr = l & 15, lg = l >> 4;
    const int n = norder[s];
    const float4* wf4 = (const float4*)(fcw + (size_t)n * CD + HS);
    const float4* wb4 = (const float4*)(fcw + (size_t)n * CD + HS + HD);
    const float4 wf0 = wf4[lr * 2], wf1 = wf4[lr * 2 + 1];
    const float4 wb0 = wb4[lr * 2], wb1 = wb4[lr * 2 + 1];
    const float dsv = ds[s];

    for (int it = 0; it < 15; ++it) {
        const int t = chunk * 60 + it * 4 + lg;
        const size_t off = ((size_t)t * BB + s) * HD + lr * 8;
        const bf16x8 hf = *(const bf16x8*)(hF + off);
        const bf16x8 hb = *(const bf16x8*)(hB + off);
        float a = 0.f;
        a = fmaf(bflo((unsigned)(ushort_t)hf[0]), wf0.x, a);
        a = fmaf(bflo((unsigned)(ushort_t)hf[1]), wf0.y, a);
        a = fmaf(bflo((unsigned)(ushort_t)hf[2]), wf0.z, a);
        a = fmaf(bflo((unsigned)(ushort_t)hf[3]), wf0.w, a);
        a = fmaf(bflo((unsigned)(ushort_t)hf[4]), wf1.x, a);
        a = fmaf(bflo((unsigned)(ushort_t)hf[5]), wf1.y, a);
        a = fmaf(bflo((unsigned)(ushort_t)hf[6]), wf1.z, a);
        a = fmaf(bflo((unsigned)(ushort_t)hf[7]), wf1.w, a);
        a = fmaf(bflo((unsigned)(ushort_t)hb[0]), wb0.x, a);
        a = fmaf(bflo((unsigned)(ushort_t)hb[1]), wb0.y, a);
        a = fmaf(bflo((unsigned)(ushort_t)hb[2]), wb0.z, a);
        a = fmaf(bflo((unsigned)(ushort_t)hb[3]), wb0.w, a);
        a = fmaf(bflo((unsigned)(ushort_t)hb[4]), wb1.x, a);
        a = fmaf(bflo((unsigned)(ushort_t)hb[5]), wb1.y, a);
        a = fmaf(bflo((unsigned)(ushort_t)hb[6]), wb1.z, a);
        a = fmaf(bflo((unsigned)(ushort_t)hb[7]), wb1.w, a);
#pragma unroll
        for (int o = 1; o < 16; o <<= 1) a += __shfl_xor(a, o);
        if (lr == 0) out[s * TT + t] = fmaxf(a + dsv, 0.f);
    }
}

// ---------------------------------------------------------------------------
extern "C" void kernel_launch(void* const* d_in, const int* in_sizes, int n_in,
                              void* d_out, int out_size, void* d_ws, size_t ws_size,
                              hipStream_t stream)
{
    const float* x_static = (const float*)d_in[0];
    const float* x_dyn    = (const float*)d_in[1];
    const int*   norder   = (const int*)d_in[2];
    const float* w_s1 = (const float*)d_in[3];  const float* b_s1 = (const float*)d_in[4];
    const float* w_s2 = (const float*)d_in[5];  const float* b_s2 = (const float*)d_in[6];
    const float* w_d  = (const float*)d_in[7];  const float* b_d  = (const float*)d_in[8];
    const float* w_ih_f = (const float*)d_in[9];  const float* w_hh_f = (const float*)d_in[10];
    const float* b_ih_f = (const float*)d_in[11]; const float* b_hh_f = (const float*)d_in[12];
    const float* w_ih_b = (const float*)d_in[13]; const float* w_hh_b = (const float*)d_in[14];
    const float* b_ih_b = (const float*)d_in[15]; const float* b_hh_b = (const float*)d_in[16];
    const float* fc_w = (const float*)d_in[17];  const float* fc_b = (const float*)d_in[18];
    float* out = (float*)d_out;

    const size_t PRE_BYTES = (size_t)BB * TT * HD * sizeof(ushort_t);  // 39,321,600
    char* p = (char*)d_ws;
    ushort_t* preF    = (ushort_t*)p;
    ushort_t* preB    = (ushort_t*)(p + PRE_BYTES);
    ushort_t* hF      = (ushort_t*)(p + 2 * PRE_BYTES);
    ushort_t* hB      = (ushort_t*)(p + 3 * PRE_BYTES);
    char* q = p + 4 * PRE_BYTES;
    ushort_t* wd_bf   = (ushort_t*)q;               q += 16384 * sizeof(ushort_t);
    ushort_t* wihf_bf = (ushort_t*)q;               q += 16384 * sizeof(ushort_t);
    ushort_t* wihb_bf = (ushort_t*)q;               q += 16384 * sizeof(ushort_t);
    ushort_t* whhf_bf = (ushort_t*)q;               q += 16384 * sizeof(ushort_t);
    ushort_t* whhb_bf = (ushort_t*)q;               q += 16384 * sizeof(ushort_t);
    float* bsf = (float*)q;                         q += 256 * sizeof(float);
    float* bsb = (float*)q;                         q += 256 * sizeof(float);
    float* ds  = (float*)q;

    prep_kernel<<<64, 256, 0, stream>>>(w_d, w_ih_f, w_ih_b, w_hh_f, w_hh_b,
                                        b_ih_f, b_hh_f, b_ih_b, b_hh_b,
                                        wd_bf, wihf_bf, wihb_bf, whhf_bf, whhb_bf, bsf, bsb);
    static_head_kernel<<<BB, 256, 0, stream>>>(x_static, norder, w_s1, b_s1, w_s2, b_s2,
                                               fc_w, fc_b, ds);
    proj_kernel<<<(BB * TT) / 128, 256, 0, stream>>>(x_dyn, wd_bf, b_d, wihf_bf, wihb_bf,
                                                     bsf, bsb, preF, preB);
    rnn_kernel<<<32, 512, 0, stream>>>(preF, preB, hF, hB, whhf_bf, whhb_bf);
    dot_kernel<<<640, 256, 0, stream>>>(hF, hB, fc_w, norder, ds, out);
}

// Round 11
// 250.231 us; speedup vs baseline: 1.2885x; 1.2885x over previous
//
#include <hip/hip_runtime.h>
#include <hip/hip_bf16.h>

#define BB 512
#define TT 300
#define IN_S 128
#define IN_D 64
#define HS 256
#define HD 128
#define CD 512  // 2*HD + HS

typedef __attribute__((ext_vector_type(8))) short bf16x8;
typedef __attribute__((ext_vector_type(4))) float f32x4;
typedef __attribute__((ext_vector_type(4))) unsigned uint4_t;
typedef unsigned short ushort_t;

static __device__ __forceinline__ ushort_t f2bf(float x) {
    unsigned u = __builtin_bit_cast(unsigned, x);
    unsigned r = (u + 0x7FFFu + ((u >> 16) & 1u)) >> 16;  // RNE
    return (ushort_t)r;
}
static __device__ __forceinline__ float bflo(unsigned u) {
    return __builtin_bit_cast(float, u << 16);
}
static __device__ __forceinline__ float bfhi(unsigned u) {
    return __builtin_bit_cast(float, u & 0xffff0000u);
}
static __device__ __forceinline__ unsigned cvt_pk(float lo, float hi) {
    unsigned r;
    asm("v_cvt_pk_bf16_f32 %0, %1, %2" : "=v"(r) : "v"(lo), "v"(hi));
    return r;
}

// ---------------------------------------------------------------------------
// prep: f32 weights -> bf16 workspace copies; fused RNN bias sums.
// ---------------------------------------------------------------------------
__global__ __launch_bounds__(256) void prep_kernel(
    const float* __restrict__ wd, const float* __restrict__ wihf, const float* __restrict__ wihb,
    const float* __restrict__ whhf, const float* __restrict__ whhb,
    const float* __restrict__ bif, const float* __restrict__ bhf,
    const float* __restrict__ bib, const float* __restrict__ bhb,
    ushort_t* __restrict__ wd_bf, ushort_t* __restrict__ wihf_bf, ushort_t* __restrict__ wihb_bf,
    ushort_t* __restrict__ whhf_bf, ushort_t* __restrict__ whhb_bf,
    float* __restrict__ bsf, float* __restrict__ bsb)
{
    const int i = blockIdx.x * 256 + threadIdx.x;  // < 16384
    if (i < HD * IN_D) wd_bf[i] = f2bf(wd[i]);
    wihf_bf[i] = f2bf(wihf[i]);
    wihb_bf[i] = f2bf(wihb[i]);
    whhf_bf[i] = f2bf(whhf[i]);
    whhb_bf[i] = f2bf(whhb[i]);
    if (i < HD) { bsf[i] = bif[i] + bhf[i]; bsb[i] = bib[i] + bhb[i]; }
}

// ---------------------------------------------------------------------------
// Kernel A (validated r0): static MLP + static head dot.
// ---------------------------------------------------------------------------
__global__ __launch_bounds__(256) void static_head_kernel(
    const float* __restrict__ xs, const int* __restrict__ norder,
    const float* __restrict__ w1, const float* __restrict__ b1,
    const float* __restrict__ w2, const float* __restrict__ b2,
    const float* __restrict__ fcw, const float* __restrict__ fcb,
    float* __restrict__ ds)
{
    __shared__ float xb[IN_S];
    __shared__ float s1[HS];
    __shared__ float red[4];
    const int b = blockIdx.x, tid = threadIdx.x;
    if (tid < IN_S) xb[tid] = xs[(size_t)b * IN_S + tid];
    __syncthreads();

    float a0 = 0.f, a1 = 0.f, a2 = 0.f, a3 = 0.f;
    {
        const float4* wsrc = (const float4*)(w1 + (size_t)tid * IN_S);
        const float4* x4 = (const float4*)xb;
#pragma unroll
        for (int i = 0; i < IN_S / 4; ++i) {
            float4 w = wsrc[i], x = x4[i];
            a0 = fmaf(w.x, x.x, a0); a1 = fmaf(w.y, x.y, a1);
            a2 = fmaf(w.z, x.z, a2); a3 = fmaf(w.w, x.w, a3);
        }
    }
    s1[tid] = fmaxf(b1[tid] + ((a0 + a1) + (a2 + a3)), 0.f);
    __syncthreads();

    a0 = a1 = a2 = a3 = 0.f;
    {
        const float4* wsrc = (const float4*)(w2 + (size_t)tid * HS);
        const float4* x4 = (const float4*)s1;
#pragma unroll
        for (int i = 0; i < HS / 4; ++i) {
            float4 w = wsrc[i], x = x4[i];
            a0 = fmaf(w.x, x.x, a0); a1 = fmaf(w.y, x.y, a1);
            a2 = fmaf(w.z, x.z, a2); a3 = fmaf(w.w, x.w, a3);
        }
    }
    float s2 = fmaxf(b2[tid] + ((a0 + a1) + (a2 + a3)), 0.f);

    const int n = norder[b];
    float p = s2 * fcw[(size_t)n * CD + tid];
#pragma unroll
    for (int o = 32; o >= 1; o >>= 1) p += __shfl_down(p, o);
    if ((tid & 63) == 0) red[tid >> 6] = p;
    __syncthreads();
    if (tid == 0) ds[b] = red[0] + red[1] + red[2] + red[3] + fcb[n];
}

// ---------------------------------------------------------------------------
// proj (validated r2, unchanged): MFMA bf16 projection + RNN input precompute.
// ---------------------------------------------------------------------------
__global__ __launch_bounds__(256) void proj_kernel(
    const float* __restrict__ xd, const ushort_t* __restrict__ wd_bf,
    const float* __restrict__ bd,
    const ushort_t* __restrict__ wihf_bf, const ushort_t* __restrict__ wihb_bf,
    const float* __restrict__ bsf, const float* __restrict__ bsb,
    ushort_t* __restrict__ preF, ushort_t* __restrict__ preB)
{
    __shared__ char lds[49152];
    char* dbase = lds;
    char* xbase = lds + 32768;
    const int tid = threadIdx.x;
    const int m0 = blockIdx.x * 128;

    {
        const int row = tid >> 1, half = tid & 1;
        const int swz = (row & 7) << 4;
        const float4* src = (const float4*)(xd + (size_t)(m0 + row) * IN_D + half * 32);
#pragma unroll
        for (int i = 0; i < 4; ++i) {
            float4 a = src[2 * i], b = src[2 * i + 1];
            bf16x8 v;
            v[0] = (short)f2bf(a.x); v[1] = (short)f2bf(a.y);
            v[2] = (short)f2bf(a.z); v[3] = (short)f2bf(a.w);
            v[4] = (short)f2bf(b.x); v[5] = (short)f2bf(b.y);
            v[6] = (short)f2bf(b.z); v[7] = (short)f2bf(b.w);
            *(bf16x8*)(xbase + ((row * 128 + half * 64 + i * 16) ^ swz)) = v;
        }
    }
    __syncthreads();

    const int w = tid >> 6, l = tid & 63;
    const int lr = l & 15, lg = l >> 4;

    f32x4 acc[2][8];
#pragma unroll
    for (int mt = 0; mt < 2; ++mt)
#pragma unroll
        for (int nt = 0; nt < 8; ++nt) acc[mt][nt] = (f32x4){0.f, 0.f, 0.f, 0.f};

    for (int kk = 0; kk < 2; ++kk) {
        bf16x8 a[2], b[8];
#pragma unroll
        for (int mt = 0; mt < 2; ++mt) {
            const int row = (w * 2 + mt) * 16 + lr;
            a[mt] = *(const bf16x8*)(xbase + ((row * 128 + kk * 64 + lg * 16) ^ ((row & 7) << 4)));
        }
#pragma unroll
        for (int nt = 0; nt < 8; ++nt)
            b[nt] = *(const bf16x8*)(wd_bf + (nt * 16 + lr) * IN_D + kk * 32 + lg * 8);
#pragma unroll
        for (int mt = 0; mt < 2; ++mt)
#pragma unroll
            for (int nt = 0; nt < 8; ++nt)
                acc[mt][nt] = __builtin_amdgcn_mfma_f32_16x16x32_bf16(a[mt], b[nt], acc[mt][nt], 0, 0, 0);
    }
#pragma unroll
    for (int nt = 0; nt < 8; ++nt) {
        const float bj = bd[nt * 16 + lr];
        const int col2 = (nt * 16 + lr) * 2;
#pragma unroll
        for (int mt = 0; mt < 2; ++mt)
#pragma unroll
            for (int r = 0; r < 4; ++r) {
                const int row = (w * 2 + mt) * 16 + lg * 4 + r;
                const float v = fmaxf(acc[mt][nt][r] + bj, 0.f);
                *(ushort_t*)(dbase + ((row * 256 + col2) ^ ((row & 7) << 4))) = f2bf(v);
            }
    }
    __syncthreads();

#pragma unroll
    for (int mat = 0; mat < 2; ++mat) {
        const ushort_t* wm = mat ? wihb_bf : wihf_bf;
        const float* bs = mat ? bsb : bsf;
        ushort_t* outp = mat ? preB : preF;

        f32x4 acc2[2][8];
#pragma unroll
        for (int mt = 0; mt < 2; ++mt)
#pragma unroll
            for (int nt = 0; nt < 8; ++nt) acc2[mt][nt] = (f32x4){0.f, 0.f, 0.f, 0.f};

        for (int kk = 0; kk < 4; ++kk) {
            bf16x8 a[2], b[8];
#pragma unroll
            for (int mt = 0; mt < 2; ++mt) {
                const int row = (w * 2 + mt) * 16 + lr;
                a[mt] = *(const bf16x8*)(dbase + ((row * 256 + kk * 64 + lg * 16) ^ ((row & 7) << 4)));
            }
#pragma unroll
            for (int nt = 0; nt < 8; ++nt)
                b[nt] = *(const bf16x8*)(wm + (nt * 16 + lr) * HD + kk * 32 + lg * 8);
#pragma unroll
            for (int mt = 0; mt < 2; ++mt)
#pragma unroll
                for (int nt = 0; nt < 8; ++nt)
                    acc2[mt][nt] = __builtin_amdgcn_mfma_f32_16x16x32_bf16(a[mt], b[nt], acc2[mt][nt], 0, 0, 0);
        }
        float bsv[8];
#pragma unroll
        for (int nt = 0; nt < 8; ++nt) bsv[nt] = bs[nt * 16 + lr];
#pragma unroll
        for (int mt = 0; mt < 2; ++mt)
#pragma unroll
            for (int r = 0; r < 4; ++r) {
                const unsigned m = (unsigned)(m0 + (w * 2 + mt) * 16 + lg * 4 + r);
                const unsigned s = m / TT, t = m % TT;
                ushort_t* rowp = outp + ((size_t)t * BB + s) * HD;
#pragma unroll
                for (int nt = 0; nt < 8; ++nt)
                    rowp[nt * 16 + lr] = f2bf(acc2[mt][nt][r] + bsv[nt]);
            }
    }
}

// ---------------------------------------------------------------------------
// rnn v11: 8-wave j-split, ONE chain per block (no cross-chain coupling).
// 64 blocks x 512 threads; wave w owns j-tile jt=w: 4 MFMAs split 2+2
// (two independent 2-deep chains + v_add), 4 ds_read_b128 (full h),
// 1 LDS uint2 write, global h-store AFTER the barrier (overlaps next
// step's ds_reads). Depth-3 pre prefetch; vmcnt never drained in-loop.
// ---------------------------------------------------------------------------
__global__ __launch_bounds__(512, 1) void rnn_kernel(
    const ushort_t* __restrict__ preF, const ushort_t* __restrict__ preB,
    ushort_t* __restrict__ hF, ushort_t* __restrict__ hB,
    const ushort_t* __restrict__ whhF, const ushort_t* __restrict__ whhB)
{
    __shared__ char hlds[8192];  // 2 x [16 samples][128 j] bf16, XOR-swizzled
    const int bid = blockIdx.x;       // 64 blocks = 32 groups x 2 dirs
    const int dir = bid & 1;
    const int s0 = (bid >> 1) * 16;
    const ushort_t* __restrict__ pre = dir ? preB : preF;
    ushort_t* __restrict__ hout = dir ? hB : hF;
    const ushort_t* __restrict__ whh = dir ? whhB : whhF;

    const int tid = threadIdx.x;
    const int w = tid >> 6;           // 0..7 = j-tile
    const int l = tid & 63;
    const int lr = l & 15, lg = l >> 4;

    const int jt = w;
    const int jb = (jt & 3) * 32 + lg * 8 + (jt >> 2) * 4;  // quad base (D layout)

    // A fragments (permuted rows): row = pi(jt, lr)
    bf16x8 A[4];
#pragma unroll
    for (int kk = 0; kk < 4; ++kk) {
        const int row = (jt & 3) * 32 + (lr >> 2) * 8 + (jt >> 2) * 4 + (lr & 3);
        A[kk] = *(const bf16x8*)(whh + (size_t)row * HD + kk * 32 + lg * 8);
    }

    const int dt = dir ? -1 : 1;
    const int t0 = dir ? (TT - 1) : 0;
    const int row_off = (s0 + lr) * HD;
    const int swz = (lr & 7) << 4;

    // zero h buffer 0 (h_{-1} = 0): 512 threads x 8B = 4096B
    *(uint2*)(hlds + tid * 8) = (uint2){0u, 0u};

    // depth-3 register prefetch of this wave's pre quad (1 uint2 per step)
    uint2 pA, pB, pC;
    {
        pA = *(const uint2*)(pre + (size_t)t0 * (BB * HD) + row_off + jb);
        pB = *(const uint2*)(pre + (size_t)(t0 + dt) * (BB * HD) + row_off + jb);
        pC = *(const uint2*)(pre + (size_t)(t0 + 2 * dt) * (BB * HD) + row_off + jb);
    }
    __syncthreads();  // once before the loop (full drain fine here)

    int t = t0;
    int cur = 0;

#define RNN_STEP(P)                                                            \
    {                                                                          \
        bf16x8 Bq[4];                                                          \
        _Pragma("unroll")                                                      \
        for (int kk = 0; kk < 4; ++kk)                                         \
            Bq[kk] = *(const bf16x8*)(hlds + cur * 4096 +                      \
                                      ((lr * 256 + kk * 64 + lg * 16) ^ swz)); \
        f32x4 accA, accB;                                                      \
        accA[0] = bflo(P.x); accA[1] = bfhi(P.x);                              \
        accA[2] = bflo(P.y); accA[3] = bfhi(P.y);                              \
        accB = (f32x4){0.f, 0.f, 0.f, 0.f};                                    \
        {   /* issue prefetch for t+3 early (hides under MFMA) */              \
            const int tp = t + 3 * dt;                                         \
            const int tc = tp < 0 ? 0 : (tp >= TT ? TT - 1 : tp);              \
            P = *(const uint2*)(pre + (size_t)tc * (BB * HD) + row_off + jb);  \
        }                                                                      \
        accA = __builtin_amdgcn_mfma_f32_16x16x32_bf16(A[0], Bq[0], accA, 0, 0, 0); \
        accB = __builtin_amdgcn_mfma_f32_16x16x32_bf16(A[2], Bq[2], accB, 0, 0, 0); \
        accA = __builtin_amdgcn_mfma_f32_16x16x32_bf16(A[1], Bq[1], accA, 0, 0, 0); \
        accB = __builtin_amdgcn_mfma_f32_16x16x32_bf16(A[3], Bq[3], accB, 0, 0, 0); \
        const float v0 = fmaxf(accA[0] + accB[0], 0.f);                        \
        const float v1 = fmaxf(accA[1] + accB[1], 0.f);                        \
        const float v2 = fmaxf(accA[2] + accB[2], 0.f);                        \
        const float v3 = fmaxf(accA[3] + accB[3], 0.f);                        \
        const uint2 q = {cvt_pk(v0, v1), cvt_pk(v2, v3)};                      \
        *(uint2*)(hlds + (cur ^ 1) * 4096 + ((lr * 256 + jb * 2) ^ swz)) = q;  \
        asm volatile("s_waitcnt lgkmcnt(0)" ::: "memory");                     \
        __builtin_amdgcn_s_barrier();                                          \
        /* global h store AFTER the barrier: overlaps next step's ds_reads */  \
        *(uint2*)(hout + (size_t)t * (BB * HD) + row_off + jb) = q;            \
        t += dt;                                                               \
        cur ^= 1;                                                              \
    }

    for (int it = 0; it < TT / 3; ++it) {
        RNN_STEP(pA);
        RNN_STEP(pB);
        RNN_STEP(pC);
    }
#undef RNN_STEP
}

// ---------------------------------------------------------------------------
// dot (validated r2): out[s*T+t] = relu(ds[s] + hf[t,s,:].wgf + hb[t,s,:].wgb)
// ---------------------------------------------------------------------------
__global__ __launch_bounds__(256) void dot_kernel(
    const ushort_t* __restrict__ hF, const ushort_t* __restrict__ hB,
    const float* __restrict__ fcw, const int* __restrict__ norder,
    const float* __restrict__ ds, float* __restrict__ out)
{
    const int gw = blockIdx.x * 4 + (threadIdx.x >> 6);  // < 2560
    const int s = gw / 5, chunk = gw % 5;
    const int l = threadIdx.x & 63, lr = l & 15, lg = l >> 4;
    const int n = norder[s];
    const float4* wf4 = (const float4*)(fcw + (size_t)n * CD + HS);
    const float4* wb4 = (const float4*)(fcw + (size_t)n * CD + HS + HD);
    const float4 wf0 = wf4[lr * 2], wf1 = wf4[lr * 2 + 1];
    const float4 wb0 = wb4[lr * 2], wb1 = wb4[lr * 2 + 1];
    const float dsv = ds[s];

    for (int it = 0; it < 15; ++it) {
        const int t = chunk * 60 + it * 4 + lg;
        const size_t off = ((size_t)t * BB + s) * HD + lr * 8;
        const bf16x8 hf = *(const bf16x8*)(hF + off);
        const bf16x8 hb = *(const bf16x8*)(hB + off);
        float a = 0.f;
        a = fmaf(bflo((unsigned)(ushort_t)hf[0]), wf0.x, a);
        a = fmaf(bflo((unsigned)(ushort_t)hf[1]), wf0.y, a);
        a = fmaf(bflo((unsigned)(ushort_t)hf[2]), wf0.z, a);
        a = fmaf(bflo((unsigned)(ushort_t)hf[3]), wf0.w, a);
        a = fmaf(bflo((unsigned)(ushort_t)hf[4]), wf1.x, a);
        a = fmaf(bflo((unsigned)(ushort_t)hf[5]), wf1.y, a);
        a = fmaf(bflo((unsigned)(ushort_t)hf[6]), wf1.z, a);
        a = fmaf(bflo((unsigned)(ushort_t)hf[7]), wf1.w, a);
        a = fmaf(bflo((unsigned)(ushort_t)hb[0]), wb0.x, a);
        a = fmaf(bflo((unsigned)(ushort_t)hb[1]), wb0.y, a);
        a = fmaf(bflo((unsigned)(ushort_t)hb[2]), wb0.z, a);
        a = fmaf(bflo((unsigned)(ushort_t)hb[3]), wb0.w, a);
        a = fmaf(bflo((unsigned)(ushort_t)hb[4]), wb1.x, a);
        a = fmaf(bflo((unsigned)(ushort_t)hb[5]), wb1.y, a);
        a = fmaf(bflo((unsigned)(ushort_t)hb[6]), wb1.z, a);
        a = fmaf(bflo((unsigned)(ushort_t)hb[7]), wb1.w, a);
#pragma unroll
        for (int o = 1; o < 16; o <<= 1) a += __shfl_xor(a, o);
        if (lr == 0) out[s * TT + t] = fmaxf(a + dsv, 0.f);
    }
}

// ---------------------------------------------------------------------------
extern "C" void kernel_launch(void* const* d_in, const int* in_sizes, int n_in,
                              void* d_out, int out_size, void* d_ws, size_t ws_size,
                              hipStream_t stream)
{
    const float* x_static = (const float*)d_in[0];
    const float* x_dyn    = (const float*)d_in[1];
    const int*   norder   = (const int*)d_in[2];
    const float* w_s1 = (const float*)d_in[3];  const float* b_s1 = (const float*)d_in[4];
    const float* w_s2 = (const float*)d_in[5];  const float* b_s2 = (const float*)d_in[6];
    const float* w_d  = (const float*)d_in[7];  const float* b_d  = (const float*)d_in[8];
    const float* w_ih_f = (const float*)d_in[9];  const float* w_hh_f = (const float*)d_in[10];
    const float* b_ih_f = (const float*)d_in[11]; const float* b_hh_f = (const float*)d_in[12];
    const float* w_ih_b = (const float*)d_in[13]; const float* w_hh_b = (const float*)d_in[14];
    const float* b_ih_b = (const float*)d_in[15]; const float* b_hh_b = (const float*)d_in[16];
    const float* fc_w = (const float*)d_in[17];  const float* fc_b = (const float*)d_in[18];
    float* out = (float*)d_out;

    const size_t PRE_BYTES = (size_t)BB * TT * HD * sizeof(ushort_t);  // 39,321,600
    char* p = (char*)d_ws;
    ushort_t* preF    = (ushort_t*)p;
    ushort_t* preB    = (ushort_t*)(p + PRE_BYTES);
    ushort_t* hF      = (ushort_t*)(p + 2 * PRE_BYTES);
    ushort_t* hB      = (ushort_t*)(p + 3 * PRE_BYTES);
    char* q = p + 4 * PRE_BYTES;
    ushort_t* wd_bf   = (ushort_t*)q;               q += 16384 * sizeof(ushort_t);
    ushort_t* wihf_bf = (ushort_t*)q;               q += 16384 * sizeof(ushort_t);
    ushort_t* wihb_bf = (ushort_t*)q;               q += 16384 * sizeof(ushort_t);
    ushort_t* whhf_bf = (ushort_t*)q;               q += 16384 * sizeof(ushort_t);
    ushort_t* whhb_bf = (ushort_t*)q;               q += 16384 * sizeof(ushort_t);
    float* bsf = (float*)q;                         q += 256 * sizeof(float);
    float* bsb = (float*)q;                         q += 256 * sizeof(float);
    float* ds  = (float*)q;

    prep_kernel<<<64, 256, 0, stream>>>(w_d, w_ih_f, w_ih_b, w_hh_f, w_hh_b,
                                        b_ih_f, b_hh_f, b_ih_b, b_hh_b,
                                        wd_bf, wihf_bf, wihb_bf, whhf_bf, whhb_bf, bsf, bsb);
    static_head_kernel<<<BB, 256, 0, stream>>>(x_static, norder, w_s1, b_s1, w_s2, b_s2,
                                               fc_w, fc_b, ds);
    proj_kernel<<<(BB * TT) / 128, 256, 0, stream>>>(x_dyn, wd_bf, b_d, wihf_bf, wihb_bf,
                                                     bsf, bsb, preF, preB);
    rnn_kernel<<<64, 512, 0, stream>>>(preF, preB, hF, hB, whhf_bf, whhb_bf);
    dot_kernel<<<640, 256, 0, stream>>>(hF, hB, fc_w, norder, ds, out);
}

// Round 12
// 201.553 us; speedup vs baseline: 1.5997x; 1.2415x over previous
//
#include <hip/hip_runtime.h>
#include <hip/hip_bf16.h>

#define BB 512
#define TT 300
#define IN_S 128
#define IN_D 64
#define HS 256
#define HD 128
#define CD 512  // 2*HD + HS

typedef __attribute__((ext_vector_type(8))) short bf16x8;
typedef __attribute__((ext_vector_type(4))) float f32x4;
typedef __attribute__((ext_vector_type(4))) unsigned uint4_t;
typedef unsigned short ushort_t;

static __device__ __forceinline__ ushort_t f2bf(float x) {
    unsigned u = __builtin_bit_cast(unsigned, x);
    unsigned r = (u + 0x7FFFu + ((u >> 16) & 1u)) >> 16;  // RNE
    return (ushort_t)r;
}
static __device__ __forceinline__ float bflo(unsigned u) {
    return __builtin_bit_cast(float, u << 16);
}
static __device__ __forceinline__ float bfhi(unsigned u) {
    return __builtin_bit_cast(float, u & 0xffff0000u);
}
static __device__ __forceinline__ unsigned cvt_pk(float lo, float hi) {
    unsigned r;
    asm("v_cvt_pk_bf16_f32 %0, %1, %2" : "=v"(r) : "v"(lo), "v"(hi));
    return r;
}

// ---------------------------------------------------------------------------
// prep: f32 weights -> bf16 workspace copies; fused RNN bias sums.
// ---------------------------------------------------------------------------
__global__ __launch_bounds__(256) void prep_kernel(
    const float* __restrict__ wd, const float* __restrict__ wihf, const float* __restrict__ wihb,
    const float* __restrict__ whhf, const float* __restrict__ whhb,
    const float* __restrict__ bif, const float* __restrict__ bhf,
    const float* __restrict__ bib, const float* __restrict__ bhb,
    ushort_t* __restrict__ wd_bf, ushort_t* __restrict__ wihf_bf, ushort_t* __restrict__ wihb_bf,
    ushort_t* __restrict__ whhf_bf, ushort_t* __restrict__ whhb_bf,
    float* __restrict__ bsf, float* __restrict__ bsb)
{
    const int i = blockIdx.x * 256 + threadIdx.x;  // < 16384
    if (i < HD * IN_D) wd_bf[i] = f2bf(wd[i]);
    wihf_bf[i] = f2bf(wihf[i]);
    wihb_bf[i] = f2bf(wihb[i]);
    whhf_bf[i] = f2bf(whhf[i]);
    whhb_bf[i] = f2bf(whhb[i]);
    if (i < HD) { bsf[i] = bif[i] + bhf[i]; bsb[i] = bib[i] + bhb[i]; }
}

// ---------------------------------------------------------------------------
// Kernel A (validated r0): static MLP + static head dot.
// ---------------------------------------------------------------------------
__global__ __launch_bounds__(256) void static_head_kernel(
    const float* __restrict__ xs, const int* __restrict__ norder,
    const float* __restrict__ w1, const float* __restrict__ b1,
    const float* __restrict__ w2, const float* __restrict__ b2,
    const float* __restrict__ fcw, const float* __restrict__ fcb,
    float* __restrict__ ds)
{
    __shared__ float xb[IN_S];
    __shared__ float s1[HS];
    __shared__ float red[4];
    const int b = blockIdx.x, tid = threadIdx.x;
    if (tid < IN_S) xb[tid] = xs[(size_t)b * IN_S + tid];
    __syncthreads();

    float a0 = 0.f, a1 = 0.f, a2 = 0.f, a3 = 0.f;
    {
        const float4* wsrc = (const float4*)(w1 + (size_t)tid * IN_S);
        const float4* x4 = (const float4*)xb;
#pragma unroll
        for (int i = 0; i < IN_S / 4; ++i) {
            float4 w = wsrc[i], x = x4[i];
            a0 = fmaf(w.x, x.x, a0); a1 = fmaf(w.y, x.y, a1);
            a2 = fmaf(w.z, x.z, a2); a3 = fmaf(w.w, x.w, a3);
        }
    }
    s1[tid] = fmaxf(b1[tid] + ((a0 + a1) + (a2 + a3)), 0.f);
    __syncthreads();

    a0 = a1 = a2 = a3 = 0.f;
    {
        const float4* wsrc = (const float4*)(w2 + (size_t)tid * HS);
        const float4* x4 = (const float4*)s1;
#pragma unroll
        for (int i = 0; i < HS / 4; ++i) {
            float4 w = wsrc[i], x = x4[i];
            a0 = fmaf(w.x, x.x, a0); a1 = fmaf(w.y, x.y, a1);
            a2 = fmaf(w.z, x.z, a2); a3 = fmaf(w.w, x.w, a3);
        }
    }
    float s2 = fmaxf(b2[tid] + ((a0 + a1) + (a2 + a3)), 0.f);

    const int n = norder[b];
    float p = s2 * fcw[(size_t)n * CD + tid];
#pragma unroll
    for (int o = 32; o >= 1; o >>= 1) p += __shfl_down(p, o);
    if ((tid & 63) == 0) red[tid >> 6] = p;
    __syncthreads();
    if (tid == 0) ds[b] = red[0] + red[1] + red[2] + red[3] + fcb[n];
}

// ---------------------------------------------------------------------------
// proj (validated r2, unchanged): MFMA bf16 projection + RNN input precompute.
// ---------------------------------------------------------------------------
__global__ __launch_bounds__(256) void proj_kernel(
    const float* __restrict__ xd, const ushort_t* __restrict__ wd_bf,
    const float* __restrict__ bd,
    const ushort_t* __restrict__ wihf_bf, const ushort_t* __restrict__ wihb_bf,
    const float* __restrict__ bsf, const float* __restrict__ bsb,
    ushort_t* __restrict__ preF, ushort_t* __restrict__ preB)
{
    __shared__ char lds[49152];
    char* dbase = lds;
    char* xbase = lds + 32768;
    const int tid = threadIdx.x;
    const int m0 = blockIdx.x * 128;

    {
        const int row = tid >> 1, half = tid & 1;
        const int swz = (row & 7) << 4;
        const float4* src = (const float4*)(xd + (size_t)(m0 + row) * IN_D + half * 32);
#pragma unroll
        for (int i = 0; i < 4; ++i) {
            float4 a = src[2 * i], b = src[2 * i + 1];
            bf16x8 v;
            v[0] = (short)f2bf(a.x); v[1] = (short)f2bf(a.y);
            v[2] = (short)f2bf(a.z); v[3] = (short)f2bf(a.w);
            v[4] = (short)f2bf(b.x); v[5] = (short)f2bf(b.y);
            v[6] = (short)f2bf(b.z); v[7] = (short)f2bf(b.w);
            *(bf16x8*)(xbase + ((row * 128 + half * 64 + i * 16) ^ swz)) = v;
        }
    }
    __syncthreads();

    const int w = tid >> 6, l = tid & 63;
    const int lr = l & 15, lg = l >> 4;

    f32x4 acc[2][8];
#pragma unroll
    for (int mt = 0; mt < 2; ++mt)
#pragma unroll
        for (int nt = 0; nt < 8; ++nt) acc[mt][nt] = (f32x4){0.f, 0.f, 0.f, 0.f};

    for (int kk = 0; kk < 2; ++kk) {
        bf16x8 a[2], b[8];
#pragma unroll
        for (int mt = 0; mt < 2; ++mt) {
            const int row = (w * 2 + mt) * 16 + lr;
            a[mt] = *(const bf16x8*)(xbase + ((row * 128 + kk * 64 + lg * 16) ^ ((row & 7) << 4)));
        }
#pragma unroll
        for (int nt = 0; nt < 8; ++nt)
            b[nt] = *(const bf16x8*)(wd_bf + (nt * 16 + lr) * IN_D + kk * 32 + lg * 8);
#pragma unroll
        for (int mt = 0; mt < 2; ++mt)
#pragma unroll
            for (int nt = 0; nt < 8; ++nt)
                acc[mt][nt] = __builtin_amdgcn_mfma_f32_16x16x32_bf16(a[mt], b[nt], acc[mt][nt], 0, 0, 0);
    }
#pragma unroll
    for (int nt = 0; nt < 8; ++nt) {
        const float bj = bd[nt * 16 + lr];
        const int col2 = (nt * 16 + lr) * 2;
#pragma unroll
        for (int mt = 0; mt < 2; ++mt)
#pragma unroll
            for (int r = 0; r < 4; ++r) {
                const int row = (w * 2 + mt) * 16 + lg * 4 + r;
                const float v = fmaxf(acc[mt][nt][r] + bj, 0.f);
                *(ushort_t*)(dbase + ((row * 256 + col2) ^ ((row & 7) << 4))) = f2bf(v);
            }
    }
    __syncthreads();

#pragma unroll
    for (int mat = 0; mat < 2; ++mat) {
        const ushort_t* wm = mat ? wihb_bf : wihf_bf;
        const float* bs = mat ? bsb : bsf;
        ushort_t* outp = mat ? preB : preF;

        f32x4 acc2[2][8];
#pragma unroll
        for (int mt = 0; mt < 2; ++mt)
#pragma unroll
            for (int nt = 0; nt < 8; ++nt) acc2[mt][nt] = (f32x4){0.f, 0.f, 0.f, 0.f};

        for (int kk = 0; kk < 4; ++kk) {
            bf16x8 a[2], b[8];
#pragma unroll
            for (int mt = 0; mt < 2; ++mt) {
                const int row = (w * 2 + mt) * 16 + lr;
                a[mt] = *(const bf16x8*)(dbase + ((row * 256 + kk * 64 + lg * 16) ^ ((row & 7) << 4)));
            }
#pragma unroll
            for (int nt = 0; nt < 8; ++nt)
                b[nt] = *(const bf16x8*)(wm + (nt * 16 + lr) * HD + kk * 32 + lg * 8);
#pragma unroll
            for (int mt = 0; mt < 2; ++mt)
#pragma unroll
                for (int nt = 0; nt < 8; ++nt)
                    acc2[mt][nt] = __builtin_amdgcn_mfma_f32_16x16x32_bf16(a[mt], b[nt], acc2[mt][nt], 0, 0, 0);
        }
        float bsv[8];
#pragma unroll
        for (int nt = 0; nt < 8; ++nt) bsv[nt] = bs[nt * 16 + lr];
#pragma unroll
        for (int mt = 0; mt < 2; ++mt)
#pragma unroll
            for (int r = 0; r < 4; ++r) {
                const unsigned m = (unsigned)(m0 + (w * 2 + mt) * 16 + lg * 4 + r);
                const unsigned s = m / TT, t = m % TT;
                ushort_t* rowp = outp + ((size_t)t * BB + s) * HD;
#pragma unroll
                for (int nt = 0; nt < 8; ++nt)
                    rowp[nt * 16 + lr] = f2bf(acc2[mt][nt][r] + bsv[nt]);
            }
    }
}

// ---------------------------------------------------------------------------
// rnn v12: v11's 8-wave j-split + fused per-wave head-dot partials.
// Each wave adds 4 fmaf + 2 shfl_xor (off the recurrence path) and lanes
// lg==0 store one f32 partial AFTER the barrier. h NEVER goes to HBM:
// -78.6MB h stores, -78.6MB dot reads, -1 kernel. dotP[dir][w][t][s].
// ---------------------------------------------------------------------------
__global__ __launch_bounds__(512, 1) void rnn_kernel(
    const ushort_t* __restrict__ preF, const ushort_t* __restrict__ preB,
    const ushort_t* __restrict__ whhF, const ushort_t* __restrict__ whhB,
    const float* __restrict__ fcw, const int* __restrict__ norder,
    float* __restrict__ dotP)
{
    __shared__ char hlds[8192];  // 2 x [16 samples][128 j] bf16, XOR-swizzled
    const int bid = blockIdx.x;       // 64 blocks = 32 groups x 2 dirs
    const int dir = bid & 1;
    const int s0 = (bid >> 1) * 16;
    const ushort_t* __restrict__ pre = dir ? preB : preF;
    const ushort_t* __restrict__ whh = dir ? whhB : whhF;

    const int tid = threadIdx.x;
    const int w = tid >> 6;           // 0..7 = j-tile
    const int l = tid & 63;
    const int lr = l & 15, lg = l >> 4;

    const int jt = w;
    const int jb = (jt & 3) * 32 + lg * 8 + (jt >> 2) * 4;  // quad base (D layout)

    // A fragments (permuted rows): row = pi(jt, lr)
    bf16x8 A[4];
#pragma unroll
    for (int kk = 0; kk < 4; ++kk) {
        const int row = (jt & 3) * 32 + (lr >> 2) * 8 + (jt >> 2) * 4 + (lr & 3);
        A[kk] = *(const bf16x8*)(whh + (size_t)row * HD + kk * 32 + lg * 8);
    }

    // head weights for this lane's j-quad; lane lr = sample (v5/v8-validated)
    const int n = norder[s0 + lr];
    const float* wrow = fcw + (size_t)n * CD + HS + dir * HD;
    float wg0 = wrow[jb], wg1 = wrow[jb + 1], wg2 = wrow[jb + 2], wg3 = wrow[jb + 3];

    // partial-dot output slice for this (dir, wave)
    float* __restrict__ dotW = dotP + ((size_t)(dir * 8 + w) * TT) * BB;

    const int dt = dir ? -1 : 1;
    const int t0 = dir ? (TT - 1) : 0;
    const int row_off = (s0 + lr) * HD;
    const int swz = (lr & 7) << 4;

    // zero h buffer 0 (h_{-1} = 0): 512 threads x 8B = 4096B
    *(uint2*)(hlds + tid * 8) = (uint2){0u, 0u};

    // depth-3 register prefetch of this wave's pre quad (1 uint2 per step)
    uint2 pA, pB, pC;
    {
        pA = *(const uint2*)(pre + (size_t)t0 * (BB * HD) + row_off + jb);
        pB = *(const uint2*)(pre + (size_t)(t0 + dt) * (BB * HD) + row_off + jb);
        pC = *(const uint2*)(pre + (size_t)(t0 + 2 * dt) * (BB * HD) + row_off + jb);
    }
    __syncthreads();  // once before the loop (full drain fine here)

    int t = t0;
    int cur = 0;

#define RNN_STEP(P)                                                            \
    {                                                                          \
        bf16x8 Bq[4];                                                          \
        _Pragma("unroll")                                                      \
        for (int kk = 0; kk < 4; ++kk)                                         \
            Bq[kk] = *(const bf16x8*)(hlds + cur * 4096 +                      \
                                      ((lr * 256 + kk * 64 + lg * 16) ^ swz)); \
        f32x4 accA, accB;                                                      \
        accA[0] = bflo(P.x); accA[1] = bfhi(P.x);                              \
        accA[2] = bflo(P.y); accA[3] = bfhi(P.y);                              \
        accB = (f32x4){0.f, 0.f, 0.f, 0.f};                                    \
        {   /* issue prefetch for t+3 early (hides under MFMA) */              \
            const int tp = t + 3 * dt;                                         \
            const int tc = tp < 0 ? 0 : (tp >= TT ? TT - 1 : tp);              \
            P = *(const uint2*)(pre + (size_t)tc * (BB * HD) + row_off + jb);  \
        }                                                                      \
        accA = __builtin_amdgcn_mfma_f32_16x16x32_bf16(A[0], Bq[0], accA, 0, 0, 0); \
        accB = __builtin_amdgcn_mfma_f32_16x16x32_bf16(A[2], Bq[2], accB, 0, 0, 0); \
        accA = __builtin_amdgcn_mfma_f32_16x16x32_bf16(A[1], Bq[1], accA, 0, 0, 0); \
        accB = __builtin_amdgcn_mfma_f32_16x16x32_bf16(A[3], Bq[3], accB, 0, 0, 0); \
        const float v0 = fmaxf(accA[0] + accB[0], 0.f);                        \
        const float v1 = fmaxf(accA[1] + accB[1], 0.f);                        \
        const float v2 = fmaxf(accA[2] + accB[2], 0.f);                        \
        const float v3 = fmaxf(accA[3] + accB[3], 0.f);                        \
        const uint2 q = {cvt_pk(v0, v1), cvt_pk(v2, v3)};                      \
        *(uint2*)(hlds + (cur ^ 1) * 4096 + ((lr * 256 + jb * 2) ^ swz)) = q;  \
        /* head-dot partial: off the recurrence path */                        \
        float dacc = fmaf(v0, wg0, v1 * wg1) + fmaf(v2, wg2, v3 * wg3);        \
        dacc += __shfl_xor(dacc, 16);                                          \
        dacc += __shfl_xor(dacc, 32);                                          \
        asm volatile("s_waitcnt lgkmcnt(0)" ::: "memory");                     \
        __builtin_amdgcn_s_barrier();                                          \
        if (lg == 0) dotW[(size_t)t * BB + s0 + lr] = dacc;                    \
        t += dt;                                                               \
        cur ^= 1;                                                              \
    }

    for (int it = 0; it < TT / 3; ++it) {
        RNN_STEP(pA);
        RNN_STEP(pB);
        RNN_STEP(pC);
    }
#undef RNN_STEP
}

// ---------------------------------------------------------------------------
// final: out[s*T+t] = relu(ds[s] + sum_{dir,w} dotP[dw][t][s]).
// Block per t (300), thread per s (512): all 16 partial reads coalesced.
// ---------------------------------------------------------------------------
__global__ __launch_bounds__(512) void final_kernel(
    const float* __restrict__ ds, const float* __restrict__ dotP,
    float* __restrict__ out)
{
    const int t = blockIdx.x;       // < 300
    const int s = threadIdx.x;      // < 512
    float acc = ds[s];
#pragma unroll
    for (int dw = 0; dw < 16; ++dw)
        acc += dotP[((size_t)dw * TT + t) * BB + s];
    out[(size_t)s * TT + t] = fmaxf(acc, 0.f);
}

// ---------------------------------------------------------------------------
extern "C" void kernel_launch(void* const* d_in, const int* in_sizes, int n_in,
                              void* d_out, int out_size, void* d_ws, size_t ws_size,
                              hipStream_t stream)
{
    const float* x_static = (const float*)d_in[0];
    const float* x_dyn    = (const float*)d_in[1];
    const int*   norder   = (const int*)d_in[2];
    const float* w_s1 = (const float*)d_in[3];  const float* b_s1 = (const float*)d_in[4];
    const float* w_s2 = (const float*)d_in[5];  const float* b_s2 = (const float*)d_in[6];
    const float* w_d  = (const float*)d_in[7];  const float* b_d  = (const float*)d_in[8];
    const float* w_ih_f = (const float*)d_in[9];  const float* w_hh_f = (const float*)d_in[10];
    const float* b_ih_f = (const float*)d_in[11]; const float* b_hh_f = (const float*)d_in[12];
    const float* w_ih_b = (const float*)d_in[13]; const float* w_hh_b = (const float*)d_in[14];
    const float* b_ih_b = (const float*)d_in[15]; const float* b_hh_b = (const float*)d_in[16];
    const float* fc_w = (const float*)d_in[17];  const float* fc_b = (const float*)d_in[18];
    float* out = (float*)d_out;

    const size_t PRE_BYTES = (size_t)BB * TT * HD * sizeof(ushort_t);  // 39,321,600
    char* p = (char*)d_ws;
    ushort_t* preF    = (ushort_t*)p;
    ushort_t* preB    = (ushort_t*)(p + PRE_BYTES);
    char* q = p + 2 * PRE_BYTES;
    ushort_t* wd_bf   = (ushort_t*)q;               q += 16384 * sizeof(ushort_t);
    ushort_t* wihf_bf = (ushort_t*)q;               q += 16384 * sizeof(ushort_t);
    ushort_t* wihb_bf = (ushort_t*)q;               q += 16384 * sizeof(ushort_t);
    ushort_t* whhf_bf = (ushort_t*)q;               q += 16384 * sizeof(ushort_t);
    ushort_t* whhb_bf = (ushort_t*)q;               q += 16384 * sizeof(ushort_t);
    float* bsf = (float*)q;                         q += 256 * sizeof(float);
    float* bsb = (float*)q;                         q += 256 * sizeof(float);
    float* ds  = (float*)q;                         q += 512 * sizeof(float);
    float* dotP = (float*)q;                        // [16][300][512] f32 = 9.83 MB

    prep_kernel<<<64, 256, 0, stream>>>(w_d, w_ih_f, w_ih_b, w_hh_f, w_hh_b,
                                        b_ih_f, b_hh_f, b_ih_b, b_hh_b,
                                        wd_bf, wihf_bf, wihb_bf, whhf_bf, whhb_bf, bsf, bsb);
    static_head_kernel<<<BB, 256, 0, stream>>>(x_static, norder, w_s1, b_s1, w_s2, b_s2,
                                               fc_w, fc_b, ds);
    proj_kernel<<<(BB * TT) / 128, 256, 0, stream>>>(x_dyn, wd_bf, b_d, wihf_bf, wihb_bf,
                                                     bsf, bsb, preF, preB);
    rnn_kernel<<<64, 512, 0, stream>>>(preF, preB, whhf_bf, whhb_bf, fc_w, norder, dotP);
    final_kernel<<<TT, 512, 0, stream>>>(ds, dotP, out);
}

// Round 13
// 200.730 us; speedup vs baseline: 1.6062x; 1.0041x over previous
//
#include <hip/hip_runtime.h>
#include <hip/hip_bf16.h>

#define BB 512
#define TT 300
#define IN_S 128
#define IN_D 64
#define HS 256
#define HD 128
#define CD 512  // 2*HD + HS

typedef __attribute__((ext_vector_type(8))) short bf16x8;
typedef __attribute__((ext_vector_type(4))) float f32x4;
typedef __attribute__((ext_vector_type(4))) unsigned uint4_t;
typedef unsigned short ushort_t;

static __device__ __forceinline__ ushort_t f2bf(float x) {
    unsigned u = __builtin_bit_cast(unsigned, x);
    unsigned r = (u + 0x7FFFu + ((u >> 16) & 1u)) >> 16;  // RNE
    return (ushort_t)r;
}
static __device__ __forceinline__ float bflo(unsigned u) {
    return __builtin_bit_cast(float, u << 16);
}
static __device__ __forceinline__ float bfhi(unsigned u) {
    return __builtin_bit_cast(float, u & 0xffff0000u);
}
static __device__ __forceinline__ unsigned cvt_pk(float lo, float hi) {
    unsigned r;
    asm("v_cvt_pk_bf16_f32 %0, %1, %2" : "=v"(r) : "v"(lo), "v"(hi));
    return r;
}

// ---------------------------------------------------------------------------
// prep: f32 weights -> bf16 workspace copies; fused RNN bias sums.
// ---------------------------------------------------------------------------
__global__ __launch_bounds__(256) void prep_kernel(
    const float* __restrict__ wd, const float* __restrict__ wihf, const float* __restrict__ wihb,
    const float* __restrict__ whhf, const float* __restrict__ whhb,
    const float* __restrict__ bif, const float* __restrict__ bhf,
    const float* __restrict__ bib, const float* __restrict__ bhb,
    ushort_t* __restrict__ wd_bf, ushort_t* __restrict__ wihf_bf, ushort_t* __restrict__ wihb_bf,
    ushort_t* __restrict__ whhf_bf, ushort_t* __restrict__ whhb_bf,
    float* __restrict__ bsf, float* __restrict__ bsb)
{
    const int i = blockIdx.x * 256 + threadIdx.x;  // < 16384
    if (i < HD * IN_D) wd_bf[i] = f2bf(wd[i]);
    wihf_bf[i] = f2bf(wihf[i]);
    wihb_bf[i] = f2bf(wihb[i]);
    whhf_bf[i] = f2bf(whhf[i]);
    whhb_bf[i] = f2bf(whhb[i]);
    if (i < HD) { bsf[i] = bif[i] + bhf[i]; bsb[i] = bib[i] + bhb[i]; }
}

// ---------------------------------------------------------------------------
// Kernel A (validated r0): static MLP + static head dot.
// ---------------------------------------------------------------------------
__global__ __launch_bounds__(256) void static_head_kernel(
    const float* __restrict__ xs, const int* __restrict__ norder,
    const float* __restrict__ w1, const float* __restrict__ b1,
    const float* __restrict__ w2, const float* __restrict__ b2,
    const float* __restrict__ fcw, const float* __restrict__ fcb,
    float* __restrict__ ds)
{
    __shared__ float xb[IN_S];
    __shared__ float s1[HS];
    __shared__ float red[4];
    const int b = blockIdx.x, tid = threadIdx.x;
    if (tid < IN_S) xb[tid] = xs[(size_t)b * IN_S + tid];
    __syncthreads();

    float a0 = 0.f, a1 = 0.f, a2 = 0.f, a3 = 0.f;
    {
        const float4* wsrc = (const float4*)(w1 + (size_t)tid * IN_S);
        const float4* x4 = (const float4*)xb;
#pragma unroll
        for (int i = 0; i < IN_S / 4; ++i) {
            float4 w = wsrc[i], x = x4[i];
            a0 = fmaf(w.x, x.x, a0); a1 = fmaf(w.y, x.y, a1);
            a2 = fmaf(w.z, x.z, a2); a3 = fmaf(w.w, x.w, a3);
        }
    }
    s1[tid] = fmaxf(b1[tid] + ((a0 + a1) + (a2 + a3)), 0.f);
    __syncthreads();

    a0 = a1 = a2 = a3 = 0.f;
    {
        const float4* wsrc = (const float4*)(w2 + (size_t)tid * HS);
        const float4* x4 = (const float4*)s1;
#pragma unroll
        for (int i = 0; i < HS / 4; ++i) {
            float4 w = wsrc[i], x = x4[i];
            a0 = fmaf(w.x, x.x, a0); a1 = fmaf(w.y, x.y, a1);
            a2 = fmaf(w.z, x.z, a2); a3 = fmaf(w.w, x.w, a3);
        }
    }
    float s2 = fmaxf(b2[tid] + ((a0 + a1) + (a2 + a3)), 0.f);

    const int n = norder[b];
    float p = s2 * fcw[(size_t)n * CD + tid];
#pragma unroll
    for (int o = 32; o >= 1; o >>= 1) p += __shfl_down(p, o);
    if ((tid & 63) == 0) red[tid >> 6] = p;
    __syncthreads();
    if (tid == 0) ds[b] = red[0] + red[1] + red[2] + red[3] + fcb[n];
}

// ---------------------------------------------------------------------------
// proj v13: same MFMA structure as validated r2 kernel, but pre is stored
// m-major ([s][t][j], row = m*HD): each block writes ONE contiguous 32KB
// region instead of 32B segments scattered across 2400 t-slabs. This is the
// write-efficiency fix for the 982 GB/s plateau. Also removes the t/s div.
// ---------------------------------------------------------------------------
__global__ __launch_bounds__(256) void proj_kernel(
    const float* __restrict__ xd, const ushort_t* __restrict__ wd_bf,
    const float* __restrict__ bd,
    const ushort_t* __restrict__ wihf_bf, const ushort_t* __restrict__ wihb_bf,
    const float* __restrict__ bsf, const float* __restrict__ bsb,
    ushort_t* __restrict__ preF, ushort_t* __restrict__ preB)
{
    __shared__ char lds[49152];
    char* dbase = lds;
    char* xbase = lds + 32768;
    const int tid = threadIdx.x;
    const int m0 = blockIdx.x * 128;

    {
        const int row = tid >> 1, half = tid & 1;
        const int swz = (row & 7) << 4;
        const float4* src = (const float4*)(xd + (size_t)(m0 + row) * IN_D + half * 32);
#pragma unroll
        for (int i = 0; i < 4; ++i) {
            float4 a = src[2 * i], b = src[2 * i + 1];
            bf16x8 v;
            v[0] = (short)f2bf(a.x); v[1] = (short)f2bf(a.y);
            v[2] = (short)f2bf(a.z); v[3] = (short)f2bf(a.w);
            v[4] = (short)f2bf(b.x); v[5] = (short)f2bf(b.y);
            v[6] = (short)f2bf(b.z); v[7] = (short)f2bf(b.w);
            *(bf16x8*)(xbase + ((row * 128 + half * 64 + i * 16) ^ swz)) = v;
        }
    }
    __syncthreads();

    const int w = tid >> 6, l = tid & 63;
    const int lr = l & 15, lg = l >> 4;

    f32x4 acc[2][8];
#pragma unroll
    for (int mt = 0; mt < 2; ++mt)
#pragma unroll
        for (int nt = 0; nt < 8; ++nt) acc[mt][nt] = (f32x4){0.f, 0.f, 0.f, 0.f};

    for (int kk = 0; kk < 2; ++kk) {
        bf16x8 a[2], b[8];
#pragma unroll
        for (int mt = 0; mt < 2; ++mt) {
            const int row = (w * 2 + mt) * 16 + lr;
            a[mt] = *(const bf16x8*)(xbase + ((row * 128 + kk * 64 + lg * 16) ^ ((row & 7) << 4)));
        }
#pragma unroll
        for (int nt = 0; nt < 8; ++nt)
            b[nt] = *(const bf16x8*)(wd_bf + (nt * 16 + lr) * IN_D + kk * 32 + lg * 8);
#pragma unroll
        for (int mt = 0; mt < 2; ++mt)
#pragma unroll
            for (int nt = 0; nt < 8; ++nt)
                acc[mt][nt] = __builtin_amdgcn_mfma_f32_16x16x32_bf16(a[mt], b[nt], acc[mt][nt], 0, 0, 0);
    }
#pragma unroll
    for (int nt = 0; nt < 8; ++nt) {
        const float bj = bd[nt * 16 + lr];
        const int col2 = (nt * 16 + lr) * 2;
#pragma unroll
        for (int mt = 0; mt < 2; ++mt)
#pragma unroll
            for (int r = 0; r < 4; ++r) {
                const int row = (w * 2 + mt) * 16 + lg * 4 + r;
                const float v = fmaxf(acc[mt][nt][r] + bj, 0.f);
                *(ushort_t*)(dbase + ((row * 256 + col2) ^ ((row & 7) << 4))) = f2bf(v);
            }
    }
    __syncthreads();

#pragma unroll
    for (int mat = 0; mat < 2; ++mat) {
        const ushort_t* wm = mat ? wihb_bf : wihf_bf;
        const float* bs = mat ? bsb : bsf;
        ushort_t* outp = mat ? preB : preF;

        f32x4 acc2[2][8];
#pragma unroll
        for (int mt = 0; mt < 2; ++mt)
#pragma unroll
            for (int nt = 0; nt < 8; ++nt) acc2[mt][nt] = (f32x4){0.f, 0.f, 0.f, 0.f};

        for (int kk = 0; kk < 4; ++kk) {
            bf16x8 a[2], b[8];
#pragma unroll
            for (int mt = 0; mt < 2; ++mt) {
                const int row = (w * 2 + mt) * 16 + lr;
                a[mt] = *(const bf16x8*)(dbase + ((row * 256 + kk * 64 + lg * 16) ^ ((row & 7) << 4)));
            }
#pragma unroll
            for (int nt = 0; nt < 8; ++nt)
                b[nt] = *(const bf16x8*)(wm + (nt * 16 + lr) * HD + kk * 32 + lg * 8);
#pragma unroll
            for (int mt = 0; mt < 2; ++mt)
#pragma unroll
                for (int nt = 0; nt < 8; ++nt)
                    acc2[mt][nt] = __builtin_amdgcn_mfma_f32_16x16x32_bf16(a[mt], b[nt], acc2[mt][nt], 0, 0, 0);
        }
        float bsv[8];
#pragma unroll
        for (int nt = 0; nt < 8; ++nt) bsv[nt] = bs[nt * 16 + lr];
#pragma unroll
        for (int mt = 0; mt < 2; ++mt)
#pragma unroll
            for (int r = 0; r < 4; ++r) {
                const unsigned m = (unsigned)(m0 + (w * 2 + mt) * 16 + lg * 4 + r);
                ushort_t* rowp = outp + (size_t)m * HD;   // m-major: contiguous block region
#pragma unroll
                for (int nt = 0; nt < 8; ++nt)
                    rowp[nt * 16 + lr] = f2bf(acc2[mt][nt][r] + bsv[nt]);
            }
    }
}

// ---------------------------------------------------------------------------
// rnn v13: v12's 8-wave j-split + fused head-dot partials, with pre read in
// m-major layout: per-lane slab base (s0+lr)*TT*HD, step offset t*HD.
// ---------------------------------------------------------------------------
__global__ __launch_bounds__(512, 1) void rnn_kernel(
    const ushort_t* __restrict__ preF, const ushort_t* __restrict__ preB,
    const ushort_t* __restrict__ whhF, const ushort_t* __restrict__ whhB,
    const float* __restrict__ fcw, const int* __restrict__ norder,
    float* __restrict__ dotP)
{
    __shared__ char hlds[8192];  // 2 x [16 samples][128 j] bf16, XOR-swizzled
    const int bid = blockIdx.x;       // 64 blocks = 32 groups x 2 dirs
    const int dir = bid & 1;
    const int s0 = (bid >> 1) * 16;
    const ushort_t* __restrict__ pre = dir ? preB : preF;
    const ushort_t* __restrict__ whh = dir ? whhB : whhF;

    const int tid = threadIdx.x;
    const int w = tid >> 6;           // 0..7 = j-tile
    const int l = tid & 63;
    const int lr = l & 15, lg = l >> 4;

    const int jt = w;
    const int jb = (jt & 3) * 32 + lg * 8 + (jt >> 2) * 4;  // quad base (D layout)

    // A fragments (permuted rows): row = pi(jt, lr)
    bf16x8 A[4];
#pragma unroll
    for (int kk = 0; kk < 4; ++kk) {
        const int row = (jt & 3) * 32 + (lr >> 2) * 8 + (jt >> 2) * 4 + (lr & 3);
        A[kk] = *(const bf16x8*)(whh + (size_t)row * HD + kk * 32 + lg * 8);
    }

    // head weights for this lane's j-quad; lane lr = sample (v5/v8-validated)
    const int n = norder[s0 + lr];
    const float* wrow = fcw + (size_t)n * CD + HS + dir * HD;
    float wg0 = wrow[jb], wg1 = wrow[jb + 1], wg2 = wrow[jb + 2], wg3 = wrow[jb + 3];

    // partial-dot output slice for this (dir, wave)
    float* __restrict__ dotW = dotP + ((size_t)(dir * 8 + w) * TT) * BB;

    const int dt = dir ? -1 : 1;
    const int t0 = dir ? (TT - 1) : 0;
    // m-major pre: per-lane slab base + jb (lane-constant), t*HD steps inside
    const ushort_t* __restrict__ lane_pre = pre + (size_t)(s0 + lr) * (TT * HD) + jb;
    const int swz = (lr & 7) << 4;

    // zero h buffer 0 (h_{-1} = 0): 512 threads x 8B = 4096B
    *(uint2*)(hlds + tid * 8) = (uint2){0u, 0u};

    // depth-3 register prefetch of this wave's pre quad (1 uint2 per step)
    uint2 pA, pB, pC;
    {
        pA = *(const uint2*)(lane_pre + (size_t)t0 * HD);
        pB = *(const uint2*)(lane_pre + (size_t)(t0 + dt) * HD);
        pC = *(const uint2*)(lane_pre + (size_t)(t0 + 2 * dt) * HD);
    }
    __syncthreads();  // once before the loop (full drain fine here)

    int t = t0;
    int cur = 0;

#define RNN_STEP(P)                                                            \
    {                                                                          \
        bf16x8 Bq[4];                                                          \
        _Pragma("unroll")                                                      \
        for (int kk = 0; kk < 4; ++kk)                                         \
            Bq[kk] = *(const bf16x8*)(hlds + cur * 4096 +                      \
                                      ((lr * 256 + kk * 64 + lg * 16) ^ swz)); \
        f32x4 accA, accB;                                                      \
        accA[0] = bflo(P.x); accA[1] = bfhi(P.x);                              \
        accA[2] = bflo(P.y); accA[3] = bfhi(P.y);                              \
        accB = (f32x4){0.f, 0.f, 0.f, 0.f};                                    \
        {   /* issue prefetch for t+3 early (hides under MFMA) */              \
            const int tp = t + 3 * dt;                                         \
            const int tc = tp < 0 ? 0 : (tp >= TT ? TT - 1 : tp);              \
            P = *(const uint2*)(lane_pre + (size_t)tc * HD);                   \
        }                                                                      \
        accA = __builtin_amdgcn_mfma_f32_16x16x32_bf16(A[0], Bq[0], accA, 0, 0, 0); \
        accB = __builtin_amdgcn_mfma_f32_16x16x32_bf16(A[2], Bq[2], accB, 0, 0, 0); \
        accA = __builtin_amdgcn_mfma_f32_16x16x32_bf16(A[1], Bq[1], accA, 0, 0, 0); \
        accB = __builtin_amdgcn_mfma_f32_16x16x32_bf16(A[3], Bq[3], accB, 0, 0, 0); \
        const float v0 = fmaxf(accA[0] + accB[0], 0.f);                        \
        const float v1 = fmaxf(accA[1] + accB[1], 0.f);                        \
        const float v2 = fmaxf(accA[2] + accB[2], 0.f);                        \
        const float v3 = fmaxf(accA[3] + accB[3], 0.f);                        \
        const uint2 q = {cvt_pk(v0, v1), cvt_pk(v2, v3)};                      \
        *(uint2*)(hlds + (cur ^ 1) * 4096 + ((lr * 256 + jb * 2) ^ swz)) = q;  \
        /* head-dot partial: off the recurrence path */                        \
        float dacc = fmaf(v0, wg0, v1 * wg1) + fmaf(v2, wg2, v3 * wg3);        \
        dacc += __shfl_xor(dacc, 16);                                          \
        dacc += __shfl_xor(dacc, 32);                                          \
        asm volatile("s_waitcnt lgkmcnt(0)" ::: "memory");                     \
        __builtin_amdgcn_s_barrier();                                          \
        if (lg == 0) dotW[(size_t)t * BB + s0 + lr] = dacc;                    \
        t += dt;                                                               \
        cur ^= 1;                                                              \
    }

    for (int it = 0; it < TT / 3; ++it) {
        RNN_STEP(pA);
        RNN_STEP(pB);
        RNN_STEP(pC);
    }
#undef RNN_STEP
}

// ---------------------------------------------------------------------------
// final: out[s*T+t] = relu(ds[s] + sum_{dir,w} dotP[dw][t][s]).
// Block per t (300), thread per s (512): all 16 partial reads coalesced.
// ---------------------------------------------------------------------------
__global__ __launch_bounds__(512) void final_kernel(
    const float* __restrict__ ds, const float* __restrict__ dotP,
    float* __restrict__ out)
{
    const int t = blockIdx.x;       // < 300
    const int s = threadIdx.x;      // < 512
    float acc = ds[s];
#pragma unroll
    for (int dw = 0; dw < 16; ++dw)
        acc += dotP[((size_t)dw * TT + t) * BB + s];
    out[(size_t)s * TT + t] = fmaxf(acc, 0.f);
}

// ---------------------------------------------------------------------------
extern "C" void kernel_launch(void* const* d_in, const int* in_sizes, int n_in,
                              void* d_out, int out_size, void* d_ws, size_t ws_size,
                              hipStream_t stream)
{
    const float* x_static = (const float*)d_in[0];
    const float* x_dyn    = (const float*)d_in[1];
    const int*   norder   = (const int*)d_in[2];
    const float* w_s1 = (const float*)d_in[3];  const float* b_s1 = (const float*)d_in[4];
    const float* w_s2 = (const float*)d_in[5];  const float* b_s2 = (const float*)d_in[6];
    const float* w_d  = (const float*)d_in[7];  const float* b_d  = (const float*)d_in[8];
    const float* w_ih_f = (const float*)d_in[9];  const float* w_hh_f = (const float*)d_in[10];
    const float* b_ih_f = (const float*)d_in[11]; const float* b_hh_f = (const float*)d_in[12];
    const float* w_ih_b = (const float*)d_in[13]; const float* w_hh_b = (const float*)d_in[14];
    const float* b_ih_b = (const float*)d_in[15]; const float* b_hh_b = (const float*)d_in[16];
    const float* fc_w = (const float*)d_in[17];  const float* fc_b = (const float*)d_in[18];
    float* out = (float*)d_out;

    const size_t PRE_BYTES = (size_t)BB * TT * HD * sizeof(ushort_t);  // 39,321,600
    char* p = (char*)d_ws;
    ushort_t* preF    = (ushort_t*)p;
    ushort_t* preB    = (ushort_t*)(p + PRE_BYTES);
    char* q = p + 2 * PRE_BYTES;
    ushort_t* wd_bf   = (ushort_t*)q;               q += 16384 * sizeof(ushort_t);
    ushort_t* wihf_bf = (ushort_t*)q;               q += 16384 * sizeof(ushort_t);
    ushort_t* wihb_bf = (ushort_t*)q;               q += 16384 * sizeof(ushort_t);
    ushort_t* whhf_bf = (ushort_t*)q;               q += 16384 * sizeof(ushort_t);
    ushort_t* whhb_bf = (ushort_t*)q;               q += 16384 * sizeof(ushort_t);
    float* bsf = (float*)q;                         q += 256 * sizeof(float);
    float* bsb = (float*)q;                         q += 256 * sizeof(float);
    float* ds  = (float*)q;                         q += 512 * sizeof(float);
    float* dotP = (float*)q;                        // [16][300][512] f32 = 9.83 MB

    prep_kernel<<<64, 256, 0, stream>>>(w_d, w_ih_f, w_ih_b, w_hh_f, w_hh_b,
                                        b_ih_f, b_hh_f, b_ih_b, b_hh_b,
                                        wd_bf, wihf_bf, wihb_bf, whhf_bf, whhb_bf, bsf, bsb);
    static_head_kernel<<<BB, 256, 0, stream>>>(x_static, norder, w_s1, b_s1, w_s2, b_s2,
                                               fc_w, fc_b, ds);
    proj_kernel<<<(BB * TT) / 128, 256, 0, stream>>>(x_dyn, wd_bf, b_d, wihf_bf, wihb_bf,
                                                     bsf, bsb, preF, preB);
    rnn_kernel<<<64, 512, 0, stream>>>(preF, preB, whhf_bf, whhb_bf, fc_w, norder, dotP);
    final_kernel<<<TT, 512, 0, stream>>>(ds, dotP, out);
}